// Round 1
// baseline (865.687 us; speedup 1.0000x reference)
//
#include <hip/hip_runtime.h>
#include <hip/hip_bf16.h>

#define T_TOK 8192
#define HDIM  1024
#define FDIM  4096
#define NEXP  8

typedef __attribute__((ext_vector_type(8))) short short8;
typedef __attribute__((ext_vector_type(4))) float f32x4;
typedef unsigned short u16;
typedef unsigned int   u32;

// ---------------- ws layout (bytes) ----------------
#define XB_OFF    0ull                          // x bf16: T*H*2      = 16,777,216
#define W1B_OFF   (XB_OFF   + 16777216ull)      // w1 bf16: E*F*H*2   = 67,108,864
#define W3B_OFF   (W1B_OFF  + 67108864ull)
#define W2B_OFF   (W3B_OFF  + 67108864ull)
#define HBUF_OFF  (W2B_OFF  + 67108864ull)      // h bf16: 2T*F*2     = 134,217,728
#define CNT_OFF   (HBUF_OFF + 134217728ull)     // E ints
#define HOFF_OFF  (CNT_OFF  + 64ull)            // E+1 ints
#define TLIST_OFF (HOFF_OFF + 64ull)            // E*T ints  = 262,144
#define WLIST_OFF (TLIST_OFF + 262144ull)       // E*T float = 262,144
#define WS_NEED   (WLIST_OFF + 262144ull)

__device__ __forceinline__ u16 f2bf(float f) {           // RNE fp32 -> bf16
  u32 u = __float_as_uint(f);
  return (u16)((u + 0x7fffu + ((u >> 16) & 1u)) >> 16);
}

__device__ __forceinline__ void gl_lds16(const void* g, void* l) {
  __builtin_amdgcn_global_load_lds(
      (const __attribute__((address_space(1))) void*)g,
      (__attribute__((address_space(3))) void*)l, 16, 0, 0);
}

// ---------------- fp32 -> bf16 weight conversion ----------------
__global__ __launch_bounds__(256) void convert_kernel(const float* __restrict__ src,
                                                      u16* __restrict__ dst, int n4) {
  int stride = gridDim.x * blockDim.x;
  for (int i = blockIdx.x * blockDim.x + threadIdx.x; i < n4; i += stride) {
    float4 v = ((const float4*)src)[i];
    u32 lo = (u32)f2bf(v.x) | ((u32)f2bf(v.y) << 16);
    u32 hi = (u32)f2bf(v.z) | ((u32)f2bf(v.w) << 16);
    ((uint2*)dst)[i] = make_uint2(lo, hi);
  }
}

// ---------------- router: logits (fp32), top-2, lists; fused x->bf16 ----------------
__global__ __launch_bounds__(256) void router_kernel(
    const float* __restrict__ x, const float* __restrict__ gw,
    float* __restrict__ logits, u16* __restrict__ xb,
    int* __restrict__ counts, int* __restrict__ tlist, float* __restrict__ wlist) {
  const int wid = threadIdx.x >> 6, lane = threadIdx.x & 63;
  const int t = blockIdx.x * 4 + wid;           // one wave per token
  const float* xr = x + (size_t)t * HDIM + lane * 16;
  float4 xv[4];
#pragma unroll
  for (int q = 0; q < 4; ++q) xv[q] = ((const float4*)xr)[q];

  // fused bf16 conversion of x (32B/lane)
  u32 pk[8];
#pragma unroll
  for (int q = 0; q < 4; ++q) {
    pk[q * 2 + 0] = (u32)f2bf(xv[q].x) | ((u32)f2bf(xv[q].y) << 16);
    pk[q * 2 + 1] = (u32)f2bf(xv[q].z) | ((u32)f2bf(xv[q].w) << 16);
  }
  u32* xbo = (u32*)(xb + (size_t)t * HDIM + lane * 16);
  ((uint4*)xbo)[0] = make_uint4(pk[0], pk[1], pk[2], pk[3]);
  ((uint4*)xbo)[1] = make_uint4(pk[4], pk[5], pk[6], pk[7]);

  float lg[NEXP];
#pragma unroll
  for (int e = 0; e < NEXP; ++e) {
    const float4* g = (const float4*)(gw + (size_t)e * HDIM + lane * 16);
    float s = 0.f;
#pragma unroll
    for (int q = 0; q < 4; ++q) {
      float4 gv = g[q];
      s += xv[q].x * gv.x + xv[q].y * gv.y + xv[q].z * gv.z + xv[q].w * gv.w;
    }
#pragma unroll
    for (int off = 32; off > 0; off >>= 1) s += __shfl_xor(s, off, 64);
    lg[e] = s;
  }
  if (lane == 0) {
    float* lo = logits + (size_t)t * NEXP;
#pragma unroll
    for (int e = 0; e < NEXP; ++e) lo[e] = lg[e];
    // top-2, lowest index wins ties (matches lax.top_k)
    float v1 = -1e30f, v2 = -1e30f; int i1 = 0, i2 = 0;
#pragma unroll
    for (int e = 0; e < NEXP; ++e) {
      float le = lg[e];
      if (le > v1)      { v2 = v1; i2 = i1; v1 = le; i1 = e; }
      else if (le > v2) { v2 = le; i2 = e; }
    }
    float t2 = __expf(v2 - v1);
    float rs = 1.f / (1.f + t2);
    int p1 = atomicAdd(&counts[i1], 1);
    tlist[i1 * T_TOK + p1] = t; wlist[i1 * T_TOK + p1] = rs;
    int p2 = atomicAdd(&counts[i2], 1);
    tlist[i2 * T_TOK + p2] = t; wlist[i2 * T_TOK + p2] = t2 * rs;
  }
}

__global__ void prefix_kernel(const int* __restrict__ counts, int* __restrict__ hoff) {
  if (threadIdx.x == 0) {
    int s = 0;
    for (int e = 0; e < NEXP; ++e) { hoff[e] = s; s += counts[e]; }
    hoff[NEXP] = s;
  }
}

// ---------------- FFN1: h = silu(x@w1^T) * (x@w3^T), grouped per expert ----------------
// 128x128 tile, BK=64, 4 waves (2x2), global_load_lds 16B, XOR chunk swizzle.
__global__ __launch_bounds__(256, 2) void ffn1_kernel(
    const u16* __restrict__ xb, const u16* __restrict__ w1b, const u16* __restrict__ w3b,
    u16* __restrict__ hbuf, const int* __restrict__ counts, const int* __restrict__ hoff,
    const int* __restrict__ tlist) {
  const int bid = blockIdx.x;
  const int e  = bid & 7;          // expert == XCD (heuristic L2 locality)
  const int j  = bid >> 3;         // 0..2047
  const int ct = j >> 6;           // F col tile 0..31 (panel)
  const int rt = j & 63;           // row tile, fastest -> B panel stays in L2
  const int Ne = counts[e];
  if (rt * 128 >= Ne) return;

  __shared__ u16 Alds[128 * 64];
  __shared__ u16 B1lds[128 * 64];
  __shared__ u16 B3lds[128 * 64];

  const int tid = threadIdx.x;
  const int wid = tid >> 6, lane = tid & 63;
  const int wr = wid >> 1, wc = wid & 1;
  const int lr = lane & 15, lhi = lane >> 4;

  // staging addresses (k0-invariant parts)
  size_t aoff[4], boff[4]; int ldso[4];
#pragma unroll
  for (int q = 0; q < 4; ++q) {
    int i = wid * 4 + q;
    int r = i * 8 + (lane >> 3);
    int sw = ((lane & 7) ^ (r & 7)) * 8;       // inverse swizzle on SOURCE (rule #21)
    int grow = rt * 128 + r;
    int gi = grow < Ne ? grow : Ne - 1;
    int tok = tlist[e * T_TOK + gi];
    aoff[q] = (size_t)tok * HDIM + sw;
    int fr = ct * 128 + r;
    boff[q] = ((size_t)e * FDIM + fr) * HDIM + sw;
    ldso[q] = i * 512;                          // u16 units = i*1024B
  }

  f32x4 acc1[4][4] = {}; f32x4 acc3[4][4] = {};

  for (int k0 = 0; k0 < HDIM; k0 += 64) {
    __syncthreads();
#pragma unroll
    for (int q = 0; q < 4; ++q) {
      gl_lds16(xb  + aoff[q] + k0, Alds  + ldso[q]);
      gl_lds16(w1b + boff[q] + k0, B1lds + ldso[q]);
      gl_lds16(w3b + boff[q] + k0, B3lds + ldso[q]);
    }
    __syncthreads();
#pragma unroll
    for (int kk = 0; kk < 2; ++kk) {
      const int swo = ((kk * 4 + lhi) ^ (lr & 7)) * 8;  // swizzled READ
      short8 af[4], b1f[4], b3f[4];
#pragma unroll
      for (int m = 0; m < 4; ++m)
        af[m] = *(const short8*)(Alds + (wr * 64 + m * 16 + lr) * 64 + swo);
#pragma unroll
      for (int n = 0; n < 4; ++n) {
        int o = (wc * 64 + n * 16 + lr) * 64 + swo;
        b1f[n] = *(const short8*)(B1lds + o);
        b3f[n] = *(const short8*)(B3lds + o);
      }
#pragma unroll
      for (int m = 0; m < 4; ++m)
#pragma unroll
        for (int n = 0; n < 4; ++n) {
          acc1[m][n] = __builtin_amdgcn_mfma_f32_16x16x32_bf16(af[m], b1f[n], acc1[m][n], 0, 0, 0);
          acc3[m][n] = __builtin_amdgcn_mfma_f32_16x16x32_bf16(af[m], b3f[n], acc3[m][n], 0, 0, 0);
        }
    }
  }

  // epilogue: silu(acc1)*acc3 -> bf16 h
  const int hb = hoff[e];
  const int rbase = rt * 128 + wr * 64 + lhi * 4;
  const int cbase = ct * 128 + wc * 64 + lr;
#pragma unroll
  for (int m = 0; m < 4; ++m)
#pragma unroll
    for (int i = 0; i < 4; ++i) {
      int grow = rbase + m * 16 + i;
      if (grow < Ne) {
        size_t rowp = (size_t)(hb + grow) * FDIM + cbase;
#pragma unroll
        for (int n = 0; n < 4; ++n) {
          float a1 = acc1[m][n][i], a3 = acc3[m][n][i];
          float hv = (a1 / (1.f + __expf(-a1))) * a3;
          hbuf[rowp + n * 16] = f2bf(hv);
        }
      }
    }
}

// ---------------- FFN2: out[tok] += w * (h @ w2^T) ----------------
__global__ __launch_bounds__(256, 2) void ffn2_kernel(
    const u16* __restrict__ hbuf, const u16* __restrict__ w2b,
    float* __restrict__ out, const int* __restrict__ counts, const int* __restrict__ hoff,
    const int* __restrict__ tlist, const float* __restrict__ wlist) {
  const int bid = blockIdx.x;
  const int e  = bid & 7;
  const int j  = bid >> 3;         // 0..511
  const int ct = j >> 6;           // H col tile 0..7
  const int rt = j & 63;
  const int Ne = counts[e];
  if (rt * 128 >= Ne) return;
  const int hb = hoff[e];

  __shared__ u16 Alds[128 * 64];
  __shared__ u16 Blds[128 * 64];

  const int tid = threadIdx.x;
  const int wid = tid >> 6, lane = tid & 63;
  const int wr = wid >> 1, wc = wid & 1;
  const int lr = lane & 15, lhi = lane >> 4;

  size_t aoff[4], boff[4]; int ldso[4];
#pragma unroll
  for (int q = 0; q < 4; ++q) {
    int i = wid * 4 + q;
    int r = i * 8 + (lane >> 3);
    int sw = ((lane & 7) ^ (r & 7)) * 8;
    int grow = rt * 128 + r;
    int gi = grow < Ne ? grow : Ne - 1;
    aoff[q] = (size_t)(hb + gi) * FDIM + sw;
    int hr = ct * 128 + r;
    boff[q] = ((size_t)e * HDIM + hr) * FDIM + sw;
    ldso[q] = i * 512;
  }

  f32x4 acc[4][4] = {};

  for (int k0 = 0; k0 < FDIM; k0 += 64) {
    __syncthreads();
#pragma unroll
    for (int q = 0; q < 4; ++q) {
      gl_lds16(hbuf + aoff[q] + k0, Alds + ldso[q]);
      gl_lds16(w2b + boff[q] + k0, Blds + ldso[q]);
    }
    __syncthreads();
#pragma unroll
    for (int kk = 0; kk < 2; ++kk) {
      const int swo = ((kk * 4 + lhi) ^ (lr & 7)) * 8;
      short8 af[4], bf_[4];
#pragma unroll
      for (int m = 0; m < 4; ++m)
        af[m] = *(const short8*)(Alds + (wr * 64 + m * 16 + lr) * 64 + swo);
#pragma unroll
      for (int n = 0; n < 4; ++n)
        bf_[n] = *(const short8*)(Blds + (wc * 64 + n * 16 + lr) * 64 + swo);
#pragma unroll
      for (int m = 0; m < 4; ++m)
#pragma unroll
        for (int n = 0; n < 4; ++n)
          acc[m][n] = __builtin_amdgcn_mfma_f32_16x16x32_bf16(af[m], bf_[n], acc[m][n], 0, 0, 0);
    }
  }

  const int rb = rt * 128 + wr * 64 + lhi * 4;
  const int cb = ct * 128 + wc * 64 + lr;
#pragma unroll
  for (int m = 0; m < 4; ++m)
#pragma unroll
    for (int i = 0; i < 4; ++i) {
      int grow = rb + m * 16 + i;
      if (grow < Ne) {
        int tok = tlist[e * T_TOK + grow];
        float wt = wlist[e * T_TOK + grow];
        float* op = out + (size_t)tok * HDIM + cb;
#pragma unroll
        for (int n = 0; n < 4; ++n)
          atomicAdd(op + n * 16, wt * acc[m][n][i]);
      }
    }
}

extern "C" void kernel_launch(void* const* d_in, const int* in_sizes, int n_in,
                              void* d_out, int out_size, void* d_ws, size_t ws_size,
                              hipStream_t stream) {
  (void)in_sizes; (void)n_in; (void)out_size;
  if (ws_size < WS_NEED) return;  // clean failure signal if ws too small

  const float* x  = (const float*)d_in[0];
  const float* gw = (const float*)d_in[1];
  const float* w1 = (const float*)d_in[2];
  const float* w3 = (const float*)d_in[3];
  const float* w2 = (const float*)d_in[4];
  float* out = (float*)d_out;
  float* logits = out + (size_t)T_TOK * HDIM;

  char* ws = (char*)d_ws;
  u16* xb    = (u16*)(ws + XB_OFF);
  u16* w1b   = (u16*)(ws + W1B_OFF);
  u16* w3b   = (u16*)(ws + W3B_OFF);
  u16* w2b   = (u16*)(ws + W2B_OFF);
  u16* hbuf  = (u16*)(ws + HBUF_OFF);
  int* counts = (int*)(ws + CNT_OFF);
  int* hoffp  = (int*)(ws + HOFF_OFF);
  int* tlist  = (int*)(ws + TLIST_OFF);
  float* wlist = (float*)(ws + WLIST_OFF);

  hipMemsetAsync(d_out, 0, (size_t)T_TOK * HDIM * sizeof(float), stream);
  hipMemsetAsync(counts, 0, NEXP * sizeof(int), stream);

  const int n4 = NEXP * FDIM * HDIM / 4;
  convert_kernel<<<4096, 256, 0, stream>>>(w1, w1b, n4);
  convert_kernel<<<4096, 256, 0, stream>>>(w3, w3b, n4);
  convert_kernel<<<4096, 256, 0, stream>>>(w2, w2b, n4);
  router_kernel<<<T_TOK / 4, 256, 0, stream>>>(x, gw, logits, xb, counts, tlist, wlist);
  prefix_kernel<<<1, 64, 0, stream>>>(counts, hoffp);
  ffn1_kernel<<<NEXP * 64 * 32, 256, 0, stream>>>(xb, w1b, w3b, hbuf, counts, hoffp, tlist);
  ffn2_kernel<<<NEXP * 64 * 8, 256, 0, stream>>>(hbuf, w2b, out, counts, hoffp, tlist, wlist);
}